// Round 13
// baseline (817.947 us; speedup 1.0000x reference)
//
#include <hip/hip_runtime.h>
#include <cfloat>
#include <cmath>

// Shapes
#define T_ 16
#define R_ 200
#define W_ 50
#define FCWT 32
#define E_ 128
#define K_ 20
#define N_ 3200            // T_*R_
#define GRU_BLOCKS 6
#define PW 53              // padded P1 row width (34 rows)

// ---------------- helpers ----------------
__device__ __forceinline__ void waveReduce2(float& a, float& b) {
#pragma unroll
    for (int o = 32; o > 0; o >>= 1) {
        a += __shfl_down(a, o, 64);
        b += __shfl_down(b, o, 64);
    }
}

// ---------------- K0: LDS-tiled weight transposes + per-launch zero-init ----------------
// Tiles of 32x32 (pad 33). Coalesced reads AND writes.
// blocks: [0,192) wih 768x256 -> wihT 256x768 ; [192,384) whh ; [384,400) qw 128x128 ;
//         [400,416) kw ; [416,420) fcw 128x32 -> fcwT 32x128 ; [420] init
__global__ __launch_bounds__(256) void transpose_multi_kernel(const float* __restrict__ wih,
                                                              const float* __restrict__ whh,
                                                              const float* __restrict__ qw,
                                                              const float* __restrict__ kw,
                                                              const float* __restrict__ fcw,
                                                              float* __restrict__ wihT,
                                                              float* __restrict__ whhT,
                                                              float* __restrict__ qwT,
                                                              float* __restrict__ kwT,
                                                              float* __restrict__ fcwT,
                                                              int* __restrict__ flags,
                                                              float* __restrict__ out) {
    int b = blockIdx.x, tid = threadIdx.x;
    int tx = tid & 31, ty = tid >> 5;           // 8 rows per pass
    __shared__ float tile[32][33];
    const float* src = nullptr; float* dst = nullptr;
    int rows = 0, cols = 0, r0 = 0, c0 = 0;
    if (b < 384) {
        int m = b < 192 ? 0 : 1;
        int idx = b - m * 192;                   // 24 x 8 tiles
        src = m ? whh : wih;  dst = m ? whhT : wihT;
        rows = 768; cols = 256;
        r0 = (idx >> 3) * 32; c0 = (idx & 7) * 32;
    } else if (b < 416) {
        int m = b < 400 ? 0 : 1;
        int idx = b - 384 - m * 16;              // 4 x 4 tiles
        src = m ? kw : qw;    dst = m ? kwT : qwT;
        rows = 128; cols = 128;
        r0 = (idx >> 2) * 32; c0 = (idx & 3) * 32;
    } else if (b < 420) {
        int idx = b - 416;                       // 4 x 1 tiles
        src = fcw; dst = fcwT;
        rows = 128; cols = 32;
        r0 = idx * 32; c0 = 0;
    } else {
        if (tid < 64) flags[tid] = 0;
        if (tid == 64) out[40002] = 0.f;
        return;
    }
#pragma unroll
    for (int i = 0; i < 4; ++i) {
        int r = ty + 8 * i;
        tile[r][tx] = src[(size_t)(r0 + r) * cols + (c0 + tx)];
    }
    __syncthreads();
#pragma unroll
    for (int i = 0; i < 4; ++i) {
        int r = ty + 8 * i;                      // output row within tile (orig col)
        dst[(size_t)(c0 + r) * rows + (r0 + tx)] = tile[tx][r];
    }
}

// ---------------- K1: CWT + conv1 + raw pool-max + BN1 stats (all fused) ----------------
__global__ __launch_bounds__(256) void cwt_conv1_kernel(const float* __restrict__ x,
                                                        const float* __restrict__ wr,
                                                        const float* __restrict__ wi,
                                                        const float* __restrict__ w1,
                                                        const float* __restrict__ b1,
                                                        float* __restrict__ pooled1max,
                                                        double* __restrict__ psum,
                                                        double* __restrict__ psq) {
    int n = blockIdx.x, tid = threadIdx.x;
    __shared__ float sxp[112];
    __shared__ float swr[FCWT * W_];
    __shared__ float swi[FCWT * W_];
    __shared__ float P1[34 * PW];
    __shared__ float ls[256], lq[256];
    __shared__ float outb[6400];
    if (tid < 112) sxp[tid] = (tid >= 24 && tid < 74) ? x[n * 50 + (tid - 24)] : 0.f;
    for (int idx = tid; idx < FCWT * W_; idx += 256) { swr[idx] = wr[idx]; swi[idx] = wi[idx]; }
    for (int idx = tid; idx < 34 * PW; idx += 256) P1[idx] = 0.f;
    __syncthreads();
    {
        int f = tid >> 3, cg = tid & 7, i0 = cg * 7;
        float xw[7], ar[7], ai[7];
#pragma unroll
        for (int d = 0; d < 7; ++d) { xw[d] = sxp[i0 + d]; ar[d] = 0.f; ai[d] = 0.f; }
        const float* wrf = &swr[f * 50];
        const float* wif = &swi[f * 50];
        for (int j = 0; j < 50; ++j) {
            float wrv = wrf[j], wiv = wif[j];
#pragma unroll
            for (int d = 0; d < 7; ++d) { ar[d] += xw[d] * wrv; ai[d] += xw[d] * wiv; }
#pragma unroll
            for (int d = 0; d < 6; ++d) xw[d] = xw[d + 1];
            xw[6] = sxp[i0 + j + 7];
        }
#pragma unroll
        for (int d = 0; d < 7; ++d) {
            int i = i0 + d;
            if (i < 50) P1[(f + 1) * PW + i + 1] = sqrtf(ar[d] * ar[d] + ai[d] * ai[d]);
        }
    }
    __syncthreads();
    int c = tid & 15, py = tid >> 4;
    float wv[9];
#pragma unroll
    for (int k = 0; k < 9; ++k) wv[k] = w1[c * 9 + k];
    float bias = b1[c];
    const float* r0p = &P1[(2 * py + 0) * PW];
    const float* r1p = &P1[(2 * py + 1) * PW];
    const float* r2p = &P1[(2 * py + 2) * PW];
    const float* r3p = &P1[(2 * py + 3) * PW];
    float c0[4], c1[4];
    c0[0] = r0p[0]; c0[1] = r1p[0]; c0[2] = r2p[0]; c0[3] = r3p[0];
    c1[0] = r0p[1]; c1[1] = r1p[1]; c1[2] = r2p[1]; c1[3] = r3p[1];
    float s = 0.f, q = 0.f, pmax = -FLT_MAX;
    for (int xx = 0; xx < 50; ++xx) {
        float c2[4];
        c2[0] = r0p[xx + 2]; c2[1] = r1p[xx + 2]; c2[2] = r2p[xx + 2]; c2[3] = r3p[xx + 2];
        float v0 = bias + c0[0] * wv[0] + c1[0] * wv[1] + c2[0] * wv[2]
                        + c0[1] * wv[3] + c1[1] * wv[4] + c2[1] * wv[5]
                        + c0[2] * wv[6] + c1[2] * wv[7] + c2[2] * wv[8];
        float v1 = bias + c0[1] * wv[0] + c1[1] * wv[1] + c2[1] * wv[2]
                        + c0[2] * wv[3] + c1[2] * wv[4] + c2[2] * wv[5]
                        + c0[3] * wv[6] + c1[3] * wv[7] + c2[3] * wv[8];
        s += v0 + v1; q += v0 * v0 + v1 * v1;
        float m2 = fmaxf(v0, v1);
        if ((xx & 1) == 0) pmax = m2;
        else outb[(c * 16 + py) * 25 + (xx >> 1)] = fmaxf(pmax, m2);
#pragma unroll
        for (int rr = 0; rr < 4; ++rr) { c0[rr] = c1[rr]; c1[rr] = c2[rr]; }
    }
    ls[tid] = s; lq[tid] = q;
    __syncthreads();
    if (tid < 16) {
        float ss = 0.f, qq = 0.f;
        for (int g = 0; g < 16; ++g) { ss += ls[tid + 16 * g]; qq += lq[tid + 16 * g]; }
        psum[n * 16 + tid] = (double)ss;
        psq[n * 16 + tid] = (double)qq;
    }
    const float4* ob4 = (const float4*)outb;
    float4* p4 = (float4*)(pooled1max + (size_t)n * 6400);
    for (int idx = tid; idx < 1600; idx += 256) p4[idx] = ob4[idx];
}

// ---------------- K2: BN finalize ----------------
__global__ __launch_bounds__(256) void bn_finalize_kernel(const double* __restrict__ psum,
                                                          const double* __restrict__ psq,
                                                          const float* __restrict__ g,
                                                          const float* __restrict__ beta,
                                                          float* __restrict__ scale,
                                                          float* __restrict__ shift,
                                                          int C, double inv_count) {
    int c = blockIdx.x, tid = threadIdx.x;
    double s = 0.0, q = 0.0;
    for (int n = tid; n < N_; n += 256) { s += psum[n * C + c]; q += psq[n * C + c]; }
#pragma unroll
    for (int o = 32; o > 0; o >>= 1) { s += __shfl_down(s, o, 64); q += __shfl_down(q, o, 64); }
    __shared__ double sa[4], sb[4];
    int lane = tid & 63, wid = tid >> 6;
    if (lane == 0) { sa[wid] = s; sb[wid] = q; }
    __syncthreads();
    if (tid == 0) {
        s = sa[0] + sa[1] + sa[2] + sa[3];
        q = sb[0] + sb[1] + sb[2] + sb[3];
        double mu = s * inv_count;
        double var = q * inv_count - mu * mu;
        double rstd = 1.0 / sqrt(var + 1e-5);
        double gg = (double)g[c];
        scale[c] = (float)(gg * rstd);
        shift[c] = (float)((double)beta[c] - mu * rstd * gg);
    }
}

// ---------------- K3: conv2 single pass (R8-proven, untouched) ----------------
__global__ __launch_bounds__(256) void conv2_compute_kernel(const float* __restrict__ pooled1max,
                                                            const float* __restrict__ scale1,
                                                            const float* __restrict__ shift1,
                                                            const float* __restrict__ w2,
                                                            const float* __restrict__ b2,
                                                            float* __restrict__ mm,
                                                            double* __restrict__ psum,
                                                            double* __restrict__ psq) {
    int n = blockIdx.x, tid = threadIdx.x;
    __shared__ float P2[16 * 18 * 28];
    __shared__ float swT[144 * 32];
    __shared__ float ls[256], lq[256];
    for (int idx = tid; idx < 16 * 18 * 28; idx += 256) {
        int ci = idx / 504, rem = idx % 504, yy = rem / 28, xx = rem % 28;
        float v = 0.f;
        if (yy >= 1 && yy <= 16 && xx >= 1 && xx <= 25) {
            float raw = pooled1max[((size_t)n * 16 + ci) * 400 + (yy - 1) * 25 + (xx - 1)];
            v = fmaxf(raw * scale1[ci] + shift1[ci], 0.f);
        }
        P2[idx] = v;
    }
    for (int idx = tid; idx < 4608; idx += 256) {
        int co = idx / 144, r = idx % 144;
        swT[r * 32 + co] = w2[idx];
    }
    __syncthreads();
    int co = tid & 31, pg = tid >> 5;
    float bias = b2[co];
    float acc0[25], acc1[25];
#pragma unroll
    for (int cv = 0; cv < 25; ++cv) { acc0[cv] = bias; acc1[cv] = bias; }
    for (int ci = 0; ci < 16; ++ci) {
        const float* wb = &swT[ci * 288 + co];
        float w[9];
#pragma unroll
        for (int k = 0; k < 9; ++k) w[k] = wb[k * 32];
        const float* base = &P2[ci * 504 + (2 * pg) * 28];
#pragma unroll
        for (int iy = 0; iy < 4; ++iy) {
            float r[28];
            const float4* rp = (const float4*)(base + iy * 28);
#pragma unroll
            for (int m = 0; m < 7; ++m) {
                float4 v4 = rp[m];
                r[4 * m] = v4.x; r[4 * m + 1] = v4.y; r[4 * m + 2] = v4.z; r[4 * m + 3] = v4.w;
            }
            if (iy < 3) {
                int kb = iy * 3;
#pragma unroll
                for (int cv = 0; cv < 25; ++cv)
                    acc0[cv] += r[cv] * w[kb] + r[cv + 1] * w[kb + 1] + r[cv + 2] * w[kb + 2];
            }
            if (iy >= 1) {
                int kb = (iy - 1) * 3;
#pragma unroll
                for (int cv = 0; cv < 25; ++cv)
                    acc1[cv] += r[cv] * w[kb] + r[cv + 1] * w[kb + 1] + r[cv + 2] * w[kb + 2];
            }
        }
    }
    float s = 0.f, q = 0.f;
#pragma unroll
    for (int cv = 0; cv < 25; ++cv) {
        s += acc0[cv] + acc1[cv];
        q += acc0[cv] * acc0[cv] + acc1[cv] * acc1[cv];
    }
#pragma unroll
    for (int pc = 0; pc < 12; ++pc) {
        float v00 = acc0[2 * pc], v01 = acc0[2 * pc + 1];
        float v10 = acc1[2 * pc], v11 = acc1[2 * pc + 1];
        float mx = fmaxf(fmaxf(v00, v01), fmaxf(v10, v11));
        int cell = pg * 12 + pc;
        mm[((size_t)n * 96 + cell) * 32 + co] = mx;
    }
    ls[tid] = s; lq[tid] = q;
    __syncthreads();
    if (tid < 32) {
        float ss = 0.f, qq = 0.f;
        for (int g2 = 0; g2 < 8; ++g2) { ss += ls[tid + 32 * g2]; qq += lq[tid + 32 * g2]; }
        psum[n * 32 + tid] = (double)ss;
        psq[n * 32 + tid] = (double)qq;
    }
}

// ---------------- K4: pooled mean + FC + Q/K (fused, per n) ----------------
__global__ __launch_bounds__(256) void pm_fc_qk_kernel(const float* __restrict__ mm,
                                                       const float* __restrict__ scale,
                                                       const float* __restrict__ shift,
                                                       const float* __restrict__ fcwT,
                                                       const float* __restrict__ fc_b,
                                                       const float* __restrict__ qwT,
                                                       const float* __restrict__ q_b,
                                                       const float* __restrict__ kwT,
                                                       const float* __restrict__ k_b,
                                                       float* __restrict__ emb,
                                                       float* __restrict__ Q,
                                                       float* __restrict__ Kp) {
    int n = blockIdx.x, tid = threadIdx.x;
    int co = tid & 31, grp = tid >> 5;
    __shared__ float red[256];
    __shared__ float pm_s[32];
    __shared__ float se[128];
    float sc = scale[co], sh = shift[co];
    float acc = 0.f;
    for (int j = 0; j < 12; ++j) {
        int cell = grp * 12 + j;
        float mx = mm[((size_t)n * 96 + cell) * 32 + co];
        acc += fmaxf(mx * sc + sh, 0.f);
    }
    red[tid] = acc;
    __syncthreads();
    if (tid < 32) {
        float t = 0.f;
        for (int g = 0; g < 8; ++g) t += red[co + 32 * g];
        pm_s[tid] = t * (1.f / 96.f);
    }
    __syncthreads();
    if (tid < 128) {
        float a = fc_b[tid];
        for (int c = 0; c < 32; ++c) a += pm_s[c] * fcwT[c * 128 + tid];
        se[tid] = a;
        emb[(size_t)n * 128 + tid] = a;
    }
    __syncthreads();
    {
        int e = tid & 127, half = tid >> 7;
        const float* w = half ? kwT : qwT;
        float b = half ? k_b[e] : q_b[e];
        float a = b;
        for (int k = 0; k < 128; ++k) a += se[k] * w[k * 128 + e];
        if (half) Kp[(size_t)n * 128 + e] = a;
        else      Q[(size_t)n * 128 + e] = a;
    }
}

// ---------------- K5: attn(4 rows/block, no spill) + topk + fused linear8(X1) ----------------
__global__ __launch_bounds__(256) void attn_topk_lin_kernel(const float* __restrict__ Q,
                                                            const float* __restrict__ Kp,
                                                            const float* __restrict__ emb,
                                                            const float* __restrict__ gcn1_w,
                                                            float* __restrict__ adj,
                                                            float* __restrict__ X1) {
    int bx = blockIdx.x, t = blockIdx.y, tid = threadIdx.x;
    __shared__ float sq[4 * 128];
    __shared__ float sc[4 * 200];
    __shared__ float sin_[8 * 128];
    if (bx >= 50) {
        int n0 = ((bx - 50) * 16 + t) * 8;
        for (int idx = tid; idx < 8 * 128; idx += 256) sin_[idx] = emb[(size_t)n0 * 128 + idx];
        __syncthreads();
        float acc[8];
#pragma unroll
        for (int m = 0; m < 8; ++m) acc[m] = 0.f;
        for (int k = 0; k < 128; ++k) {
            float wv = gcn1_w[k * 256 + tid];
#pragma unroll
            for (int m = 0; m < 8; ++m) acc[m] += sin_[m * 128 + k] * wv;
        }
#pragma unroll
        for (int m = 0; m < 8; ++m) X1[(size_t)(n0 + m) * 256 + tid] = acc[m];
        return;
    }
    int r0 = 4 * bx;
    for (int idx = tid; idx < 512; idx += 256)
        sq[idx] = Q[(size_t)(t * 200 + r0 + (idx >> 7)) * 128 + (idx & 127)];
    __syncthreads();
    if (tid < 200) {
        const float4* kp4 = (const float4*)(Kp + (size_t)(t * 200 + tid) * 128);
        const float4* q0 = (const float4*)&sq[0];
        const float4* q1 = (const float4*)&sq[128];
        const float4* q2 = (const float4*)&sq[256];
        const float4* q3 = (const float4*)&sq[384];
        float a0 = 0.f, a1 = 0.f, a2 = 0.f, a3 = 0.f;
#pragma unroll 4
        for (int e4 = 0; e4 < 32; ++e4) {
            float4 k4 = kp4[e4];
            float4 qa = q0[e4];
            a0 += qa.x * k4.x + qa.y * k4.y + qa.z * k4.z + qa.w * k4.w;
            float4 qb = q1[e4];
            a1 += qb.x * k4.x + qb.y * k4.y + qb.z * k4.z + qb.w * k4.w;
            float4 qc = q2[e4];
            a2 += qc.x * k4.x + qc.y * k4.y + qc.z * k4.z + qc.w * k4.w;
            float4 qd = q3[e4];
            a3 += qd.x * k4.x + qd.y * k4.y + qd.z * k4.z + qd.w * k4.w;
        }
        const float inv_s = 1.f / 11.313708498984761f;
        a0 *= inv_s; a1 *= inv_s; a2 *= inv_s; a3 *= inv_s;
        sc[tid]       = (a0 >= 0.f) ? a0 : 0.2f * a0;
        sc[200 + tid] = (a1 >= 0.f) ? a1 : 0.2f * a1;
        sc[400 + tid] = (a2 >= 0.f) ? a2 : 0.2f * a2;
        sc[600 + tid] = (a3 >= 0.f) ? a3 : 0.2f * a3;
    }
    __syncthreads();
    {
        int wv2 = tid >> 6, lane = tid & 63;
        const float* a = &sc[wv2 * 200];
        float v[4], w[4];
#pragma unroll
        for (int j = 0; j < 4; ++j) {
            int i = lane + 64 * j;
            float x = (i < 200) ? a[i] : -FLT_MAX;
            v[j] = x; w[j] = x;
        }
        unsigned sel = 0;
        for (int it = 0; it < K_; ++it) {
            float best = -FLT_MAX; int bidx = 0x7fffffff;
#pragma unroll
            for (int j = 0; j < 4; ++j) {
                int i = lane + 64 * j;
                if (w[j] > best || (w[j] == best && i < bidx)) { best = w[j]; bidx = i; }
            }
#pragma unroll
            for (int off = 32; off > 0; off >>= 1) {
                float ob = __shfl_down(best, off, 64);
                int oi = __shfl_down(bidx, off, 64);
                if (ob > best || (ob == best && oi < bidx)) { best = ob; bidx = oi; }
            }
            bidx = __shfl(bidx, 0, 64);
            if ((bidx & 63) == lane) { int j = bidx >> 6; w[j] = -FLT_MAX; sel |= (1u << j); }
        }
        float mv[4]; float m = -FLT_MAX;
#pragma unroll
        for (int j = 0; j < 4; ++j) {
            int i = lane + 64 * j;
            float x = -1e9f;
            if (i < 200 && ((sel >> j) & 1u)) x = (v[j] == 0.f) ? -1e9f : v[j];
            mv[j] = x; m = fmaxf(m, x);
        }
#pragma unroll
        for (int off = 32; off > 0; off >>= 1) m = fmaxf(m, __shfl_xor(m, off, 64));
        float s = 0.f; float e[4];
#pragma unroll
        for (int j = 0; j < 4; ++j) {
            int i = lane + 64 * j;
            e[j] = (i < 200) ? expf(mv[j] - m) : 0.f;
            s += e[j];
        }
#pragma unroll
        for (int off = 32; off > 0; off >>= 1) s += __shfl_xor(s, off, 64);
        float inv = 1.f / s;
        size_t rowo = (size_t)(t * 200 + r0 + wv2) * 200;
#pragma unroll
        for (int j = 0; j < 4; ++j) {
            int i = lane + 64 * j;
            if (i < 200) adj[rowo + i] = e[j] * inv;
        }
    }
}

// ---------------- K6: An tiles (deg fused) + fused edge/avg_adj path ----------------
__global__ __launch_bounds__(256) void an_tile_edge_kernel(const float* __restrict__ adj,
                                                           float* __restrict__ An,
                                                           float* __restrict__ out) {
    int bx = blockIdx.x, t = blockIdx.y, tid = threadIdx.x;
    if (bx >= 16) {
        int gid = ((bx - 16) * 16 + t) * 256 + tid;
        float var = 0.f;
        if (gid < 40000) {
            float v[16]; float s = 0.f;
#pragma unroll
            for (int tt = 0; tt < 16; ++tt) { v[tt] = adj[(size_t)tt * 40000 + gid]; s += v[tt]; }
            float mean = s * (1.f / 16.f);
            float q = 0.f;
#pragma unroll
            for (int tt = 0; tt < 16; ++tt) { float d = v[tt] - mean; q += d * d; }
            var = q * (1.f / 15.f);
            out[2 + gid] = mean;
        }
        float dummy = 0.f;
        waveReduce2(var, dummy);
        __shared__ float sa[4];
        int lane = tid & 63, wid = tid >> 6;
        if (lane == 0) sa[wid] = var;
        __syncthreads();
        if (tid == 0) {
            float bs = sa[0] + sa[1] + sa[2] + sa[3];
            atomicAdd(&out[40002], bs * (1.f / 40000.f));
        }
        return;
    }
    int tr = bx >> 2, tc = bx & 3;
    int r0 = tr * 50, s0 = tc * 50;
    __shared__ float Tt[50 * 51];
    __shared__ float dr[50], ds[50];
    if (tid < 50 || (tid >= 64 && tid < 114)) {
        int col = (tid < 50) ? (r0 + tid) : (s0 + tid - 64);
        float acc = 0.f;
        for (int s = 0; s < 200; ++s) {
            float v = adj[(size_t)(t * 200 + s) * 200 + col];
            if (s == col) v = (v == 0.f) ? 1.f : v;
            acc += v;
        }
        float d = (acc > 0.f) ? acc : 1.f;
        float di = 1.f / sqrtf(d);
        if (tid < 50) dr[tid] = di;
        else ds[tid - 64] = di;
    }
    for (int idx = tid; idx < 2500; idx += 256) {
        int a = idx / 50, b = idx % 50;
        Tt[a * 51 + b] = adj[(size_t)(t * 200 + s0 + a) * 200 + r0 + b];
    }
    __syncthreads();
    for (int idx = tid; idx < 2500; idx += 256) {
        int rl = idx / 50, sl = idx % 50;
        float v = Tt[sl * 51 + rl];
        if (r0 + rl == s0 + sl) v = (v == 0.f) ? 1.f : v;
        An[(size_t)(t * 200 + r0 + rl) * 200 + s0 + sl] = dr[rl] * v * ds[sl];
    }
}

// ---------------- K7: 8-row batched linear (IN -> 256), no bias ----------------
__global__ __launch_bounds__(256) void linear8_kernel(const float* __restrict__ in,
                                                      const float* __restrict__ w,
                                                      float* __restrict__ out, int IN) {
    int n0 = blockIdx.x * 8, h = threadIdx.x;
    __shared__ float sin_[8 * 256];
    for (int idx = h; idx < 8 * IN; idx += 256) sin_[idx] = in[(size_t)n0 * IN + idx];
    __syncthreads();
    float acc[8];
#pragma unroll
    for (int m = 0; m < 8; ++m) acc[m] = 0.f;
    for (int k = 0; k < IN; ++k) {
        float wv = w[k * 256 + h];
#pragma unroll
        for (int m = 0; m < 8; ++m) acc[m] += sin_[m * IN + k] * wv;
    }
#pragma unroll
    for (int m = 0; m < 8; ++m) out[(size_t)(n0 + m) * 256 + h] = acc[m];
}

// ---------------- K8: GCN aggregation, 16 rows per block ----------------
__global__ __launch_bounds__(256) void gcn_agg16_kernel(const float* __restrict__ An,
                                                        const float* __restrict__ X,
                                                        const float* __restrict__ b,
                                                        float* __restrict__ out) {
    int t = blockIdx.y, r0 = blockIdx.x * 16, h = threadIdx.x;
    __shared__ float sa[16 * 200];
    int rows = (200 - r0 < 16) ? (200 - r0) : 16;
    for (int idx = h; idx < 3200; idx += 256)
        sa[idx] = (idx < rows * 200) ? An[(size_t)(t * 200 + r0) * 200 + idx] : 0.f;
    __syncthreads();
    const float* Xt = X + (size_t)t * 200 * 256;
    float acc[16];
#pragma unroll
    for (int m = 0; m < 16; ++m) acc[m] = 0.f;
    for (int s = 0; s < 200; ++s) {
        float xv = Xt[s * 256 + h];
#pragma unroll
        for (int m = 0; m < 16; ++m) acc[m] += sa[m * 200 + s] * xv;
    }
    float bb = b[h];
    for (int m = 0; m < rows; ++m)
        out[(size_t)(t * 200 + r0 + m) * 256 + h] = fmaxf(acc[m] + bb, 0.f);
}

// ---------------- K9: mean over R + GRU input matvec (fused, split over 3 segs) ----------------
__global__ __launch_bounds__(256) void gemb_gi_kernel(const float* __restrict__ g2,
                                                      const float* __restrict__ wihT,
                                                      const float* __restrict__ bih,
                                                      float* __restrict__ GI) {
    int t = blockIdx.x, seg = blockIdx.y, tid = threadIdx.x;
    __shared__ float sg[256];
    {
        float acc = 0.f;
        for (int r = 0; r < 200; ++r) acc += g2[(size_t)(t * 200 + r) * 256 + tid];
        sg[tid] = acc * (1.f / 200.f);
    }
    __syncthreads();
    int j = seg * 256 + tid;
    float acc = bih[j];
    for (int k = 0; k < 256; ++k) acc += sg[k] * wihT[k * 768 + j];
    GI[t * 768 + j] = acc;
}

// ---------------- K10: GRU (register weights, 6 blocks, flag sync) + classifier ----------------
__global__ __launch_bounds__(256) void gru_cls_kernel(const float* __restrict__ GI,
                                                      const float* __restrict__ whhT,
                                                      const float* __restrict__ bhh,
                                                      const float* __restrict__ cls_w,
                                                      const float* __restrict__ cls_b,
                                                      float* __restrict__ GH,
                                                      int* __restrict__ flags,
                                                      float* __restrict__ out) {
    int b = blockIdx.x, tid = threadIdx.x;
    int jl = tid & 127;
    int kc = tid >> 7;
    int j = b * 128 + jl;
    float wreg[128];
#pragma unroll 16
    for (int k = 0; k < 128; ++k)
        wreg[k] = whhT[(size_t)(kc * 128 + k) * 768 + j];
    __shared__ float hcur[256];
    __shared__ float part[256];
    __shared__ float s0[4], s1[4];
    hcur[tid] = 0.f;
    __syncthreads();
    for (int st = 0; st < 16; ++st) {
        float p = 0.f;
        const float* hb = &hcur[kc * 128];
#pragma unroll 16
        for (int k = 0; k < 128; ++k) p += hb[k] * wreg[k];
        part[tid] = p;
        __syncthreads();
        if (tid < 128) {
            GH[st * 768 + b * 128 + tid] = part[tid] + part[tid + 128];
        }
        __threadfence();
        __syncthreads();
        if (tid == 0)
            __hip_atomic_store(&flags[b], st + 1, __ATOMIC_RELEASE, __HIP_MEMORY_SCOPE_AGENT);
        for (int bb = 0; bb < GRU_BLOCKS; ++bb) {
            while (__hip_atomic_load(&flags[bb], __ATOMIC_ACQUIRE, __HIP_MEMORY_SCOPE_AGENT) <= st)
                __builtin_amdgcn_s_sleep(2);
        }
        float ghr = GH[st * 768 + tid]       + bhh[tid];
        float ghz = GH[st * 768 + 256 + tid] + bhh[256 + tid];
        float ghn = GH[st * 768 + 512 + tid] + bhh[512 + tid];
        float gir = GI[st * 768 + tid];
        float giz = GI[st * 768 + 256 + tid];
        float gin = GI[st * 768 + 512 + tid];
        float r = 1.f / (1.f + expf(-(gir + ghr)));
        float z = 1.f / (1.f + expf(-(giz + ghz)));
        float nn = tanhf(gin + r * ghn);
        float hnew = (1.f - z) * nn + z * hcur[tid];
        __syncthreads();
        hcur[tid] = hnew;
        __syncthreads();
    }
    if (b == 0) {
        float v0 = hcur[tid] * cls_w[tid];
        float v1 = hcur[tid] * cls_w[256 + tid];
        waveReduce2(v0, v1);
        int lane = tid & 63, wid = tid >> 6;
        if (lane == 0) { s0[wid] = v0; s1[wid] = v1; }
        __syncthreads();
        if (tid == 0) {
            out[0] = s0[0] + s0[1] + s0[2] + s0[3] + cls_b[0];
            out[1] = s1[0] + s1[1] + s1[2] + s1[3] + cls_b[1];
        }
    }
}

// ---------------- host ----------------
extern "C" void kernel_launch(void* const* d_in, const int* in_sizes, int n_in,
                              void* d_out, int out_size, void* d_ws, size_t ws_size,
                              hipStream_t stream) {
    const float* tw      = (const float*)d_in[0];
    const float* wav_r   = (const float*)d_in[1];
    const float* wav_i   = (const float*)d_in[2];
    const float* conv1_w = (const float*)d_in[3];
    const float* conv1_b = (const float*)d_in[4];
    const float* bn1_g   = (const float*)d_in[5];
    const float* bn1_b   = (const float*)d_in[6];
    const float* conv2_w = (const float*)d_in[7];
    const float* conv2_b = (const float*)d_in[8];
    const float* bn2_g   = (const float*)d_in[9];
    const float* bn2_b   = (const float*)d_in[10];
    const float* fc_w    = (const float*)d_in[11];
    const float* fc_b    = (const float*)d_in[12];
    const float* q_w     = (const float*)d_in[13];
    const float* q_b     = (const float*)d_in[14];
    const float* k_w     = (const float*)d_in[15];
    const float* k_b     = (const float*)d_in[16];
    const float* gcn1_w  = (const float*)d_in[17];
    const float* gcn1_b  = (const float*)d_in[18];
    const float* gcn2_w  = (const float*)d_in[19];
    const float* gcn2_b  = (const float*)d_in[20];
    const float* gru_wih = (const float*)d_in[21];
    const float* gru_whh = (const float*)d_in[22];
    const float* gru_bih = (const float*)d_in[23];
    const float* gru_bhh = (const float*)d_in[24];
    const float* cls_w   = (const float*)d_in[25];
    const float* cls_b   = (const float*)d_in[26];
    float* out = (float*)d_out;
    (void)in_sizes; (void)n_in; (void)out_size; (void)ws_size;

    const size_t POOLED1_B = (size_t)N_ * 6400 * 4;
    const size_t MM_B      = (size_t)N_ * 96 * 32 * 4;
    const size_t P1S_B     = (size_t)N_ * 16 * 8;
    const size_t P2S_B     = (size_t)N_ * 32 * 8;
    const size_t WT_B      = (size_t)768 * 256 * 4;

    size_t off = 0;
    char* Wb = (char*)d_ws;
    auto take = [&](size_t bytes) -> char* {
        char* p = Wb + off;
        off += (bytes + 255) & ~(size_t)255;
        return p;
    };
    char*  pooled1U = take(POOLED1_B);
    float* mm    = (float*)take(MM_B);
    double* p1sum = (double*)take(P1S_B);
    double* p1sq  = (double*)take(P1S_B);
    double* p2sum = (double*)take(P2S_B);
    double* p2sq  = (double*)take(P2S_B);
    float* scale1 = (float*)take(64 * 4);
    float* shift1 = (float*)take(64 * 4);
    float* scale2 = (float*)take(64 * 4);
    float* shift2 = (float*)take(64 * 4);
    float* wihT   = (float*)take(WT_B);
    float* whhT   = (float*)take(WT_B);
    float* qwT    = (float*)take(128 * 128 * 4);
    float* kwT    = (float*)take(128 * 128 * 4);
    float* fcwT   = (float*)take(32 * 128 * 4);
    float* GH     = (float*)take((size_t)16 * 768 * 4);
    int*   flags  = (int*)take(256);
    float* emb    = (float*)take((size_t)N_ * 128 * 4);
    float* Q      = (float*)take((size_t)N_ * 128 * 4);
    float* Kp     = (float*)take((size_t)N_ * 128 * 4);

    float* pooled1 = (float*)pooled1U;
    size_t moff = 0;
    auto mtake = [&](size_t bytes) -> float* {
        float* p = (float*)(pooled1U + moff);
        moff += (bytes + 255) & ~(size_t)255;
        return p;
    };
    float* adj   = mtake((size_t)T_ * 200 * 200 * 4);
    float* An    = mtake((size_t)T_ * 200 * 200 * 4);
    float* X1    = mtake((size_t)N_ * 256 * 4);
    float* g1    = mtake((size_t)N_ * 256 * 4);
    float* X2    = mtake((size_t)N_ * 256 * 4);
    float* g2    = mtake((size_t)N_ * 256 * 4);
    float* GI    = mtake((size_t)T_ * 768 * 4);

    transpose_multi_kernel<<<421, 256, 0, stream>>>(gru_wih, gru_whh, q_w, k_w, fc_w,
                                                    wihT, whhT, qwT, kwT, fcwT,
                                                    flags, out);
    cwt_conv1_kernel<<<N_, 256, 0, stream>>>(tw, wav_r, wav_i, conv1_w, conv1_b,
                                             pooled1, p1sum, p1sq);
    bn_finalize_kernel<<<16, 256, 0, stream>>>(p1sum, p1sq, bn1_g, bn1_b, scale1, shift1,
                                               16, 1.0 / 5120000.0);
    conv2_compute_kernel<<<N_, 256, 0, stream>>>(pooled1, scale1, shift1, conv2_w, conv2_b,
                                                 mm, p2sum, p2sq);
    bn_finalize_kernel<<<32, 256, 0, stream>>>(p2sum, p2sq, bn2_g, bn2_b, scale2, shift2,
                                               32, 1.0 / 1280000.0);
    pm_fc_qk_kernel<<<N_, 256, 0, stream>>>(mm, scale2, shift2, fcwT, fc_b,
                                            qwT, q_b, kwT, k_b, emb, Q, Kp);
    attn_topk_lin_kernel<<<dim3(75, 16), 256, 0, stream>>>(Q, Kp, emb, gcn1_w, adj, X1);
    an_tile_edge_kernel<<<dim3(26, 16), 256, 0, stream>>>(adj, An, out);
    gcn_agg16_kernel<<<dim3(13, 16), 256, 0, stream>>>(An, X1, gcn1_b, g1);
    linear8_kernel<<<N_ / 8, 256, 0, stream>>>(g1, gcn2_w, X2, 256);
    gcn_agg16_kernel<<<dim3(13, 16), 256, 0, stream>>>(An, X2, gcn2_b, g2);
    gemb_gi_kernel<<<dim3(16, 3), 256, 0, stream>>>(g2, wihT, gru_bih, GI);
    gru_cls_kernel<<<GRU_BLOCKS, 256, 0, stream>>>(GI, whhT, gru_bhh, cls_w, cls_b,
                                                   GH, flags, out);
}